// Round 1
// baseline (3064.372 us; speedup 1.0000x reference)
//
#include <hip/hip_runtime.h>
#include <hip/hip_bf16.h>

#define N_NODES 100000
#define N_EDGES 1600000
#define IN_DIM 128
#define HID_DIM 256
#define LN_EPS 1e-5f
#define BM 64

// ---------------------------------------------------------------------------
// Kernel 1: degree counts (out-degree from src, in-degree from dst)
// ---------------------------------------------------------------------------
__global__ void deg_kernel(const int* __restrict__ src, const int* __restrict__ dst,
                           unsigned* __restrict__ deg_out, unsigned* __restrict__ deg_in) {
    int e = blockIdx.x * blockDim.x + threadIdx.x;
    if (e < N_EDGES) {
        atomicAdd(&deg_out[src[e]], 1u);
        atomicAdd(&deg_in[dst[e]], 1u);
    }
}

// ---------------------------------------------------------------------------
// Kernel 2: edge-parallel scatter SpMM: agg[dst] += features[src] * norm_src[src]
// 32 lanes per edge, one float4 per lane (128 floats/row).
// ---------------------------------------------------------------------------
__global__ void scatter_kernel(const float* __restrict__ feat,
                               const int* __restrict__ src, const int* __restrict__ dst,
                               const unsigned* __restrict__ deg_out,
                               float* __restrict__ agg) {
    long long t = (long long)blockIdx.x * blockDim.x + threadIdx.x;
    int e = (int)(t >> 5);
    int q = (int)(t & 31);
    if (e >= N_EDGES) return;
    int s = src[e];
    int d = dst[e];
    float ns = rsqrtf(fmaxf((float)deg_out[s], 1.0f));
    float4 v = ((const float4*)(feat + (size_t)s * IN_DIM))[q];
    float* arow = agg + (size_t)d * IN_DIM + (size_t)q * 4;
    unsafeAtomicAdd(arow + 0, v.x * ns);
    unsafeAtomicAdd(arow + 1, v.y * ns);
    unsafeAtomicAdd(arow + 2, v.z * ns);
    unsafeAtomicAdd(arow + 3, v.w * ns);
}

// ---------------------------------------------------------------------------
// Kernel 3: fused  gcn = (agg * norm_dst) @ W + b ; LN ; ReLU ; += feat @ skipW + skipb
// Block = 256 threads (4 waves), BM = 64 nodes per block.
// Wave ty owns rows [ty*16, ty*16+16); lane tx owns cols [tx*4, tx*4+4).
// One wave covers all 256 cols of a row -> LayerNorm = in-wave shfl reduction.
// ---------------------------------------------------------------------------
__global__ __launch_bounds__(256)
void gemm_ln_skip_kernel(const float* __restrict__ agg, const unsigned* __restrict__ deg_in,
                         const float* __restrict__ feat,
                         const float* __restrict__ W, const float* __restrict__ bvec,
                         const float* __restrict__ gamma, const float* __restrict__ beta,
                         const float* __restrict__ skipW, const float* __restrict__ skipb,
                         float* __restrict__ out) {
    __shared__ float tile[BM][IN_DIM];   // 32 KB
    const int tid = threadIdx.x;
    const int ty = tid >> 6;     // wave id 0..3
    const int tx = tid & 63;     // lane 0..63
    const int block0 = blockIdx.x * BM;
    const int j0 = tx * 4;
    const int m0 = ty * 16;

    // ---- stage agg tile, scaled by norm_dst -------------------------------
    #pragma unroll
    for (int i = 0; i < 8; ++i) {
        int off = i * 1024 + tid * 4;
        int r = off >> 7;
        int c = off & 127;
        int node = block0 + r;
        float4 v = make_float4(0.f, 0.f, 0.f, 0.f);
        if (node < N_NODES) {
            v = *(const float4*)(agg + (size_t)node * IN_DIM + c);
            float nd = rsqrtf(fmaxf((float)deg_in[node], 1.0f));
            v.x *= nd; v.y *= nd; v.z *= nd; v.w *= nd;
        }
        *(float4*)&tile[r][c] = v;
    }
    __syncthreads();

    // ---- GEMM 1: gcn = tile @ W + b ---------------------------------------
    float acc[16][4];
    {
        float4 bv = *(const float4*)(bvec + j0);
        #pragma unroll
        for (int i = 0; i < 16; ++i) {
            acc[i][0] = bv.x; acc[i][1] = bv.y; acc[i][2] = bv.z; acc[i][3] = bv.w;
        }
    }
    for (int k = 0; k < IN_DIM; k += 4) {
        float4 w0 = *(const float4*)(W + (size_t)(k + 0) * HID_DIM + j0);
        float4 w1 = *(const float4*)(W + (size_t)(k + 1) * HID_DIM + j0);
        float4 w2 = *(const float4*)(W + (size_t)(k + 2) * HID_DIM + j0);
        float4 w3 = *(const float4*)(W + (size_t)(k + 3) * HID_DIM + j0);
        #pragma unroll
        for (int i = 0; i < 16; ++i) {
            float4 a = *(const float4*)&tile[m0 + i][k];   // wave-uniform -> LDS broadcast
            acc[i][0] = fmaf(a.x, w0.x, acc[i][0]);
            acc[i][1] = fmaf(a.x, w0.y, acc[i][1]);
            acc[i][2] = fmaf(a.x, w0.z, acc[i][2]);
            acc[i][3] = fmaf(a.x, w0.w, acc[i][3]);
            acc[i][0] = fmaf(a.y, w1.x, acc[i][0]);
            acc[i][1] = fmaf(a.y, w1.y, acc[i][1]);
            acc[i][2] = fmaf(a.y, w1.z, acc[i][2]);
            acc[i][3] = fmaf(a.y, w1.w, acc[i][3]);
            acc[i][0] = fmaf(a.z, w2.x, acc[i][0]);
            acc[i][1] = fmaf(a.z, w2.y, acc[i][1]);
            acc[i][2] = fmaf(a.z, w2.z, acc[i][2]);
            acc[i][3] = fmaf(a.z, w2.w, acc[i][3]);
            acc[i][0] = fmaf(a.w, w3.x, acc[i][0]);
            acc[i][1] = fmaf(a.w, w3.y, acc[i][1]);
            acc[i][2] = fmaf(a.w, w3.z, acc[i][2]);
            acc[i][3] = fmaf(a.w, w3.w, acc[i][3]);
        }
    }

    // ---- LayerNorm + ReLU (in-wave reduction over 256 cols) ---------------
    {
        float4 g  = *(const float4*)(gamma + j0);
        float4 bt = *(const float4*)(beta + j0);
        #pragma unroll
        for (int i = 0; i < 16; ++i) {
            float s1 = acc[i][0] + acc[i][1] + acc[i][2] + acc[i][3];
            float s2 = acc[i][0]*acc[i][0] + acc[i][1]*acc[i][1]
                     + acc[i][2]*acc[i][2] + acc[i][3]*acc[i][3];
            #pragma unroll
            for (int m = 32; m >= 1; m >>= 1) {
                s1 += __shfl_xor(s1, m, 64);
                s2 += __shfl_xor(s2, m, 64);
            }
            float mu   = s1 * (1.0f / HID_DIM);
            float var  = s2 * (1.0f / HID_DIM) - mu * mu;
            float rstd = rsqrtf(var + LN_EPS);
            acc[i][0] = fmaxf((acc[i][0] - mu) * rstd * g.x + bt.x, 0.f);
            acc[i][1] = fmaxf((acc[i][1] - mu) * rstd * g.y + bt.y, 0.f);
            acc[i][2] = fmaxf((acc[i][2] - mu) * rstd * g.z + bt.z, 0.f);
            acc[i][3] = fmaxf((acc[i][3] - mu) * rstd * g.w + bt.w, 0.f);
        }
    }

    // ---- stage features tile ----------------------------------------------
    __syncthreads();
    #pragma unroll
    for (int i = 0; i < 8; ++i) {
        int off = i * 1024 + tid * 4;
        int r = off >> 7;
        int c = off & 127;
        int node = block0 + r;
        float4 v = make_float4(0.f, 0.f, 0.f, 0.f);
        if (node < N_NODES) {
            v = *(const float4*)(feat + (size_t)node * IN_DIM + c);
        }
        *(float4*)&tile[r][c] = v;
    }
    __syncthreads();

    // ---- GEMM 2: out += feat @ skipW  (accumulates on top of relu(ln)) ----
    for (int k = 0; k < IN_DIM; k += 4) {
        float4 w0 = *(const float4*)(skipW + (size_t)(k + 0) * HID_DIM + j0);
        float4 w1 = *(const float4*)(skipW + (size_t)(k + 1) * HID_DIM + j0);
        float4 w2 = *(const float4*)(skipW + (size_t)(k + 2) * HID_DIM + j0);
        float4 w3 = *(const float4*)(skipW + (size_t)(k + 3) * HID_DIM + j0);
        #pragma unroll
        for (int i = 0; i < 16; ++i) {
            float4 a = *(const float4*)&tile[m0 + i][k];
            acc[i][0] = fmaf(a.x, w0.x, acc[i][0]);
            acc[i][1] = fmaf(a.x, w0.y, acc[i][1]);
            acc[i][2] = fmaf(a.x, w0.z, acc[i][2]);
            acc[i][3] = fmaf(a.x, w0.w, acc[i][3]);
            acc[i][0] = fmaf(a.y, w1.x, acc[i][0]);
            acc[i][1] = fmaf(a.y, w1.y, acc[i][1]);
            acc[i][2] = fmaf(a.y, w1.z, acc[i][2]);
            acc[i][3] = fmaf(a.y, w1.w, acc[i][3]);
            acc[i][0] = fmaf(a.z, w2.x, acc[i][0]);
            acc[i][1] = fmaf(a.z, w2.y, acc[i][1]);
            acc[i][2] = fmaf(a.z, w2.z, acc[i][2]);
            acc[i][3] = fmaf(a.z, w2.w, acc[i][3]);
            acc[i][0] = fmaf(a.w, w3.x, acc[i][0]);
            acc[i][1] = fmaf(a.w, w3.y, acc[i][1]);
            acc[i][2] = fmaf(a.w, w3.z, acc[i][2]);
            acc[i][3] = fmaf(a.w, w3.w, acc[i][3]);
        }
    }

    // ---- + skip_b, store ----------------------------------------------------
    {
        float4 sb = *(const float4*)(skipb + j0);
        #pragma unroll
        for (int i = 0; i < 16; ++i) {
            int node = block0 + m0 + i;
            if (node < N_NODES) {
                float4 o = make_float4(acc[i][0] + sb.x, acc[i][1] + sb.y,
                                       acc[i][2] + sb.z, acc[i][3] + sb.w);
                *(float4*)(out + (size_t)node * HID_DIM + j0) = o;
            }
        }
    }
}

// ---------------------------------------------------------------------------
extern "C" void kernel_launch(void* const* d_in, const int* in_sizes, int n_in,
                              void* d_out, int out_size, void* d_ws, size_t ws_size,
                              hipStream_t stream) {
    const float* feat  = (const float*)d_in[0];
    const int*   src   = (const int*)d_in[1];
    const int*   dst   = (const int*)d_in[2];
    const float* W     = (const float*)d_in[3];
    const float* bvec  = (const float*)d_in[4];
    const float* gamma = (const float*)d_in[5];
    const float* beta  = (const float*)d_in[6];
    const float* skipW = (const float*)d_in[7];
    const float* skipb = (const float*)d_in[8];
    float* out = (float*)d_out;

    char* ws = (char*)d_ws;
    float*    agg     = (float*)ws;                                    // N*128 f32 = 51.2 MB
    unsigned* deg_out = (unsigned*)(ws + (size_t)N_NODES * IN_DIM * 4);
    unsigned* deg_in  = deg_out + N_NODES;

    // zero agg + both degree arrays in one memset (contiguous)
    hipMemsetAsync(ws, 0, (size_t)N_NODES * IN_DIM * 4 + 2 * (size_t)N_NODES * 4, stream);

    deg_kernel<<<(N_EDGES + 255) / 256, 256, 0, stream>>>(src, dst, deg_out, deg_in);

    {
        long long total = (long long)N_EDGES * 32;
        int blocks = (int)((total + 255) / 256);
        scatter_kernel<<<blocks, 256, 0, stream>>>(feat, src, dst, deg_out, agg);
    }

    gemm_ln_skip_kernel<<<(N_NODES + BM - 1) / BM, 256, 0, stream>>>(
        agg, deg_in, feat, W, bvec, gamma, beta, skipW, skipb, out);
}

// Round 2
// 752.268 us; speedup vs baseline: 4.0735x; 4.0735x over previous
//
#include <hip/hip_runtime.h>
#include <hip/hip_bf16.h>

#define N_NODES 100000
#define N_EDGES 1600000
#define IN_DIM 128
#define HID_DIM 256
#define LN_EPS 1e-5f
#define BM 64

// ---------------------------------------------------------------------------
// Kernel 1: degree counts (out-degree from src, in-degree from dst)
// ---------------------------------------------------------------------------
__global__ void deg_kernel(const int* __restrict__ src, const int* __restrict__ dst,
                           unsigned* __restrict__ deg_out, unsigned* __restrict__ deg_in) {
    int e = blockIdx.x * blockDim.x + threadIdx.x;
    if (e < N_EDGES) {
        atomicAdd(&deg_out[src[e]], 1u);
        atomicAdd(&deg_in[dst[e]], 1u);
    }
}

// ---------------------------------------------------------------------------
// Kernel 2: single-block exclusive scan of deg_in -> row_ptr, plus nsrc table.
// 1024 threads, 16 waves; shfl-based wave scan + serial wave-sum scan.
// ---------------------------------------------------------------------------
__global__ __launch_bounds__(1024)
void scan_kernel(const unsigned* __restrict__ deg_in, const unsigned* __restrict__ deg_out,
                 unsigned* __restrict__ row_ptr, float* __restrict__ nsrc) {
    __shared__ unsigned wsum[16];
    __shared__ unsigned carry_s;
    if (threadIdx.x == 0) carry_s = 0;
    __syncthreads();
    const int lane = threadIdx.x & 63;
    const int wid = threadIdx.x >> 6;
    for (int base = 0; base < N_NODES; base += 1024) {
        int i = base + threadIdx.x;
        unsigned v = (i < N_NODES) ? deg_in[i] : 0u;
        if (i < N_NODES) nsrc[i] = rsqrtf(fmaxf((float)deg_out[i], 1.0f));
        unsigned x = v;
        #pragma unroll
        for (int d = 1; d < 64; d <<= 1) {
            unsigned t = __shfl_up(x, d, 64);
            if (lane >= d) x += t;
        }
        if (lane == 63) wsum[wid] = x;
        __syncthreads();
        if (threadIdx.x == 0) {
            unsigned run = carry_s;
            #pragma unroll
            for (int w = 0; w < 16; ++w) { unsigned t = wsum[w]; wsum[w] = run; run += t; }
            carry_s = run;
        }
        __syncthreads();
        if (i < N_NODES) row_ptr[i] = wsum[wid] + x - v;  // exclusive prefix
        __syncthreads();  // protect wsum/carry for next chunk
    }
    if (threadIdx.x == 0) row_ptr[N_NODES] = carry_s;
}

// ---------------------------------------------------------------------------
// Kernel 3: CSR fill — edge_src bucketed by dst (order within bucket arbitrary)
// ---------------------------------------------------------------------------
__global__ void fill_kernel(const int* __restrict__ src, const int* __restrict__ dst,
                            const unsigned* __restrict__ row_ptr,
                            unsigned* __restrict__ fill, unsigned* __restrict__ edge_src) {
    int e = blockIdx.x * blockDim.x + threadIdx.x;
    if (e < N_EDGES) {
        int d = dst[e];
        unsigned pos = row_ptr[d] + atomicAdd(&fill[d], 1u);
        edge_src[pos] = (unsigned)src[e];
    }
}

// ---------------------------------------------------------------------------
// Kernel 4: fused  gather-SpMM -> LDS tile ; gcn = tile @ W + b ; LN ; ReLU ;
//           += feat @ skipW + skipb
// Block = 256 threads (4 waves), BM = 64 nodes per block.
// Staging: wave ty gathers rows [ty*16, ty*16+16); lane tx holds float2 slice.
// GEMM: wave ty owns rows [ty*16,+16), lane tx owns cols [tx*4, tx*4+4).
// ---------------------------------------------------------------------------
__global__ __launch_bounds__(256)
void gcn_fused_kernel(const float* __restrict__ feat,
                      const unsigned* __restrict__ row_ptr,
                      const unsigned* __restrict__ edge_src,
                      const float* __restrict__ nsrc,
                      const float* __restrict__ W, const float* __restrict__ bvec,
                      const float* __restrict__ gamma, const float* __restrict__ beta,
                      const float* __restrict__ skipW, const float* __restrict__ skipb,
                      float* __restrict__ out) {
    __shared__ float tile[BM][IN_DIM];   // 32 KB
    const int tid = threadIdx.x;
    const int ty = tid >> 6;     // wave id 0..3
    const int tx = tid & 63;     // lane 0..63
    const int block0 = blockIdx.x * BM;
    const int j0 = tx * 4;
    const int m0 = ty * 16;

    // ---- gather-stage agg tile (scaled by norm_dst) ------------------------
    #pragma unroll 1
    for (int i = 0; i < 16; ++i) {
        const int node = block0 + m0 + i;
        float a0 = 0.f, a1 = 0.f;
        unsigned beg = 0, end = 0;
        if (node < N_NODES) { beg = row_ptr[node]; end = row_ptr[node + 1]; }
        unsigned e = beg;
        // unroll x4 to break the edge_src -> feat dependent-load chain
        for (; e + 4 <= end; e += 4) {
            unsigned s0 = edge_src[e + 0];
            unsigned s1 = edge_src[e + 1];
            unsigned s2 = edge_src[e + 2];
            unsigned s3 = edge_src[e + 3];
            float n0 = nsrc[s0], n1 = nsrc[s1], n2 = nsrc[s2], n3 = nsrc[s3];
            float2 v0 = *(const float2*)(feat + (size_t)s0 * IN_DIM + 2 * tx);
            float2 v1 = *(const float2*)(feat + (size_t)s1 * IN_DIM + 2 * tx);
            float2 v2 = *(const float2*)(feat + (size_t)s2 * IN_DIM + 2 * tx);
            float2 v3 = *(const float2*)(feat + (size_t)s3 * IN_DIM + 2 * tx);
            a0 = fmaf(v0.x, n0, a0); a1 = fmaf(v0.y, n0, a1);
            a0 = fmaf(v1.x, n1, a0); a1 = fmaf(v1.y, n1, a1);
            a0 = fmaf(v2.x, n2, a0); a1 = fmaf(v2.y, n2, a1);
            a0 = fmaf(v3.x, n3, a0); a1 = fmaf(v3.y, n3, a1);
        }
        for (; e < end; ++e) {
            unsigned s = edge_src[e];
            float ns = nsrc[s];
            float2 v = *(const float2*)(feat + (size_t)s * IN_DIM + 2 * tx);
            a0 = fmaf(v.x, ns, a0); a1 = fmaf(v.y, ns, a1);
        }
        float nd = rsqrtf(fmaxf((float)(end - beg), 1.0f));
        tile[m0 + i][2 * tx]     = a0 * nd;
        tile[m0 + i][2 * tx + 1] = a1 * nd;
    }
    __syncthreads();

    // ---- GEMM 1: gcn = tile @ W + b ---------------------------------------
    float acc[16][4];
    {
        float4 bv = *(const float4*)(bvec + j0);
        #pragma unroll
        for (int i = 0; i < 16; ++i) {
            acc[i][0] = bv.x; acc[i][1] = bv.y; acc[i][2] = bv.z; acc[i][3] = bv.w;
        }
    }
    for (int k = 0; k < IN_DIM; k += 4) {
        float4 w0 = *(const float4*)(W + (size_t)(k + 0) * HID_DIM + j0);
        float4 w1 = *(const float4*)(W + (size_t)(k + 1) * HID_DIM + j0);
        float4 w2 = *(const float4*)(W + (size_t)(k + 2) * HID_DIM + j0);
        float4 w3 = *(const float4*)(W + (size_t)(k + 3) * HID_DIM + j0);
        #pragma unroll
        for (int i = 0; i < 16; ++i) {
            float4 a = *(const float4*)&tile[m0 + i][k];   // wave-uniform -> LDS broadcast
            acc[i][0] = fmaf(a.x, w0.x, acc[i][0]);
            acc[i][1] = fmaf(a.x, w0.y, acc[i][1]);
            acc[i][2] = fmaf(a.x, w0.z, acc[i][2]);
            acc[i][3] = fmaf(a.x, w0.w, acc[i][3]);
            acc[i][0] = fmaf(a.y, w1.x, acc[i][0]);
            acc[i][1] = fmaf(a.y, w1.y, acc[i][1]);
            acc[i][2] = fmaf(a.y, w1.z, acc[i][2]);
            acc[i][3] = fmaf(a.y, w1.w, acc[i][3]);
            acc[i][0] = fmaf(a.z, w2.x, acc[i][0]);
            acc[i][1] = fmaf(a.z, w2.y, acc[i][1]);
            acc[i][2] = fmaf(a.z, w2.z, acc[i][2]);
            acc[i][3] = fmaf(a.z, w2.w, acc[i][3]);
            acc[i][0] = fmaf(a.w, w3.x, acc[i][0]);
            acc[i][1] = fmaf(a.w, w3.y, acc[i][1]);
            acc[i][2] = fmaf(a.w, w3.z, acc[i][2]);
            acc[i][3] = fmaf(a.w, w3.w, acc[i][3]);
        }
    }

    // ---- LayerNorm + ReLU (in-wave reduction over 256 cols) ---------------
    {
        float4 g  = *(const float4*)(gamma + j0);
        float4 bt = *(const float4*)(beta + j0);
        #pragma unroll
        for (int i = 0; i < 16; ++i) {
            float s1 = acc[i][0] + acc[i][1] + acc[i][2] + acc[i][3];
            float s2 = acc[i][0]*acc[i][0] + acc[i][1]*acc[i][1]
                     + acc[i][2]*acc[i][2] + acc[i][3]*acc[i][3];
            #pragma unroll
            for (int m = 32; m >= 1; m >>= 1) {
                s1 += __shfl_xor(s1, m, 64);
                s2 += __shfl_xor(s2, m, 64);
            }
            float mu   = s1 * (1.0f / HID_DIM);
            float var  = s2 * (1.0f / HID_DIM) - mu * mu;
            float rstd = rsqrtf(var + LN_EPS);
            acc[i][0] = fmaxf((acc[i][0] - mu) * rstd * g.x + bt.x, 0.f);
            acc[i][1] = fmaxf((acc[i][1] - mu) * rstd * g.y + bt.y, 0.f);
            acc[i][2] = fmaxf((acc[i][2] - mu) * rstd * g.z + bt.z, 0.f);
            acc[i][3] = fmaxf((acc[i][3] - mu) * rstd * g.w + bt.w, 0.f);
        }
    }

    // ---- stage features tile ----------------------------------------------
    __syncthreads();
    #pragma unroll
    for (int i = 0; i < 8; ++i) {
        int off = i * 1024 + tid * 4;
        int r = off >> 7;
        int c = off & 127;
        int node = block0 + r;
        float4 v = make_float4(0.f, 0.f, 0.f, 0.f);
        if (node < N_NODES) {
            v = *(const float4*)(feat + (size_t)node * IN_DIM + c);
        }
        *(float4*)&tile[r][c] = v;
    }
    __syncthreads();

    // ---- GEMM 2: out += feat @ skipW ---------------------------------------
    for (int k = 0; k < IN_DIM; k += 4) {
        float4 w0 = *(const float4*)(skipW + (size_t)(k + 0) * HID_DIM + j0);
        float4 w1 = *(const float4*)(skipW + (size_t)(k + 1) * HID_DIM + j0);
        float4 w2 = *(const float4*)(skipW + (size_t)(k + 2) * HID_DIM + j0);
        float4 w3 = *(const float4*)(skipW + (size_t)(k + 3) * HID_DIM + j0);
        #pragma unroll
        for (int i = 0; i < 16; ++i) {
            float4 a = *(const float4*)&tile[m0 + i][k];
            acc[i][0] = fmaf(a.x, w0.x, acc[i][0]);
            acc[i][1] = fmaf(a.x, w0.y, acc[i][1]);
            acc[i][2] = fmaf(a.x, w0.z, acc[i][2]);
            acc[i][3] = fmaf(a.x, w0.w, acc[i][3]);
            acc[i][0] = fmaf(a.y, w1.x, acc[i][0]);
            acc[i][1] = fmaf(a.y, w1.y, acc[i][1]);
            acc[i][2] = fmaf(a.y, w1.z, acc[i][2]);
            acc[i][3] = fmaf(a.y, w1.w, acc[i][3]);
            acc[i][0] = fmaf(a.z, w2.x, acc[i][0]);
            acc[i][1] = fmaf(a.z, w2.y, acc[i][1]);
            acc[i][2] = fmaf(a.z, w2.z, acc[i][2]);
            acc[i][3] = fmaf(a.z, w2.w, acc[i][3]);
            acc[i][0] = fmaf(a.w, w3.x, acc[i][0]);
            acc[i][1] = fmaf(a.w, w3.y, acc[i][1]);
            acc[i][2] = fmaf(a.w, w3.z, acc[i][2]);
            acc[i][3] = fmaf(a.w, w3.w, acc[i][3]);
        }
    }

    // ---- + skip_b, store ----------------------------------------------------
    {
        float4 sb = *(const float4*)(skipb + j0);
        #pragma unroll
        for (int i = 0; i < 16; ++i) {
            int node = block0 + m0 + i;
            if (node < N_NODES) {
                float4 o = make_float4(acc[i][0] + sb.x, acc[i][1] + sb.y,
                                       acc[i][2] + sb.z, acc[i][3] + sb.w);
                *(float4*)(out + (size_t)node * HID_DIM + j0) = o;
            }
        }
    }
}

// ---------------------------------------------------------------------------
extern "C" void kernel_launch(void* const* d_in, const int* in_sizes, int n_in,
                              void* d_out, int out_size, void* d_ws, size_t ws_size,
                              hipStream_t stream) {
    const float* feat  = (const float*)d_in[0];
    const int*   src   = (const int*)d_in[1];
    const int*   dst   = (const int*)d_in[2];
    const float* W     = (const float*)d_in[3];
    const float* bvec  = (const float*)d_in[4];
    const float* gamma = (const float*)d_in[5];
    const float* beta  = (const float*)d_in[6];
    const float* skipW = (const float*)d_in[7];
    const float* skipb = (const float*)d_in[8];
    float* out = (float*)d_out;

    // workspace layout (≈8.8 MB total)
    char* ws = (char*)d_ws;
    unsigned* deg_out  = (unsigned*)ws;                     // N
    unsigned* deg_in   = deg_out + N_NODES;                 // N
    unsigned* fill     = deg_in + N_NODES;                  // N   (zeroed with degs)
    unsigned* row_ptr  = fill + N_NODES;                    // N+1
    float*    nsrc     = (float*)(row_ptr + N_NODES + 1);   // N
    unsigned* edge_src = (unsigned*)(nsrc + N_NODES);       // E

    // zero deg_out, deg_in, fill in one memset (contiguous)
    hipMemsetAsync(ws, 0, (size_t)3 * N_NODES * 4, stream);

    deg_kernel<<<(N_EDGES + 255) / 256, 256, 0, stream>>>(src, dst, deg_out, deg_in);

    scan_kernel<<<1, 1024, 0, stream>>>(deg_in, deg_out, row_ptr, nsrc);

    fill_kernel<<<(N_EDGES + 255) / 256, 256, 0, stream>>>(src, dst, row_ptr, fill, edge_src);

    gcn_fused_kernel<<<(N_NODES + BM - 1) / BM, 256, 0, stream>>>(
        feat, row_ptr, edge_src, nsrc, W, bvec, gamma, beta, skipW, skipb, out);
}

// Round 3
// 546.987 us; speedup vs baseline: 5.6023x; 1.3753x over previous
//
#include <hip/hip_runtime.h>
#include <hip/hip_bf16.h>

#define N_NODES 100000
#define N_EDGES 1600000
#define IN_DIM 128
#define HID_DIM 256
#define LN_EPS 1e-5f

typedef short bf16x8 __attribute__((ext_vector_type(8)));
typedef float f32x4  __attribute__((ext_vector_type(4)));

static __device__ __forceinline__ short f2bf(float x) {
    return __builtin_bit_cast(short, __float2bfloat16(x));  // RNE round
}

// ---------------------------------------------------------------------------
// Kernel 1: degree counts
// ---------------------------------------------------------------------------
__global__ void deg_kernel(const int* __restrict__ src, const int* __restrict__ dst,
                           unsigned* __restrict__ deg_out, unsigned* __restrict__ deg_in) {
    int e = blockIdx.x * blockDim.x + threadIdx.x;
    if (e < N_EDGES) {
        atomicAdd(&deg_out[src[e]], 1u);
        atomicAdd(&deg_in[dst[e]], 1u);
    }
}

// ---------------------------------------------------------------------------
// Kernel 2: single-block exclusive scan (4 elems/thread) -> row_ptr, + nsrc
// ---------------------------------------------------------------------------
__global__ __launch_bounds__(1024)
void scan_kernel(const unsigned* __restrict__ deg_in, const unsigned* __restrict__ deg_out,
                 unsigned* __restrict__ row_ptr, float* __restrict__ nsrc) {
    __shared__ unsigned wsum[16];
    __shared__ unsigned carry_s;
    if (threadIdx.x == 0) carry_s = 0;
    __syncthreads();
    const int lane = threadIdx.x & 63;
    const int wid  = threadIdx.x >> 6;
    for (int base = 0; base < N_NODES; base += 4096) {
        int i0 = base + threadIdx.x * 4;
        unsigned d0 = 0, d1 = 0, d2 = 0, d3 = 0;
        if (i0 < N_NODES) {  // N_NODES % 4 == 0 -> quad fully in-range
            uint4 v = *(const uint4*)(deg_in + i0);
            d0 = v.x; d1 = v.y; d2 = v.z; d3 = v.w;
        }
        unsigned t = d0 + d1 + d2 + d3;
        unsigned x = t;
        #pragma unroll
        for (int d = 1; d < 64; d <<= 1) {
            unsigned tt = __shfl_up(x, d, 64);
            if (lane >= d) x += tt;
        }
        if (lane == 63) wsum[wid] = x;
        __syncthreads();
        if (threadIdx.x == 0) {
            unsigned run = carry_s;
            #pragma unroll
            for (int w = 0; w < 16; ++w) { unsigned tmp = wsum[w]; wsum[w] = run; run += tmp; }
            carry_s = run;
        }
        __syncthreads();
        if (i0 < N_NODES) {
            unsigned b = wsum[wid] + (x - t);   // exclusive prefix for this quad
            uint4 rp;
            rp.x = b; rp.y = b + d0; rp.z = b + d0 + d1; rp.w = b + d0 + d1 + d2;
            *(uint4*)(row_ptr + i0) = rp;
            uint4 dq = *(const uint4*)(deg_out + i0);
            float4 ns;
            ns.x = rsqrtf(fmaxf((float)dq.x, 1.f));
            ns.y = rsqrtf(fmaxf((float)dq.y, 1.f));
            ns.z = rsqrtf(fmaxf((float)dq.z, 1.f));
            ns.w = rsqrtf(fmaxf((float)dq.w, 1.f));
            *(float4*)(nsrc + i0) = ns;
        }
        __syncthreads();
    }
    if (threadIdx.x == 0) row_ptr[N_NODES] = carry_s;
}

// ---------------------------------------------------------------------------
// Kernel 3: CSR fill (bucket edges by dst)
// ---------------------------------------------------------------------------
__global__ void fill_kernel(const int* __restrict__ src, const int* __restrict__ dst,
                            const unsigned* __restrict__ row_ptr,
                            unsigned* __restrict__ fill, unsigned* __restrict__ edge_src) {
    int e = blockIdx.x * blockDim.x + threadIdx.x;
    if (e < N_EDGES) {
        int d = dst[e];
        unsigned pos = row_ptr[d] + atomicAdd(&fill[d], 1u);
        edge_src[pos] = (unsigned)src[e];
    }
}

// ---------------------------------------------------------------------------
// Kernel 4: W / skipW -> bf16, transposed to [HID_DIM][IN_DIM] (N-major)
// ---------------------------------------------------------------------------
__global__ void wcvt_kernel(const float* __restrict__ W, const float* __restrict__ sW,
                            ushort* __restrict__ Wt, ushort* __restrict__ sWt) {
    int id = blockIdx.x * blockDim.x + threadIdx.x;
    if (id < IN_DIM * HID_DIM) {
        int k = id & (IN_DIM - 1);
        int n = id >> 7;
        Wt[n * IN_DIM + k]  = (ushort)f2bf(W[k * HID_DIM + n]);
        sWt[n * IN_DIM + k] = (ushort)f2bf(sW[k * HID_DIM + n]);
    }
}

// ---------------------------------------------------------------------------
// Kernel 5: row-per-wave gather SpMM -> aggb (bf16), norm_dst applied
// ---------------------------------------------------------------------------
__global__ __launch_bounds__(256)
void spmm_kernel(const float* __restrict__ feat,
                 const unsigned* __restrict__ row_ptr, const unsigned* __restrict__ edge_src,
                 const float* __restrict__ nsrc, ushort* __restrict__ aggb) {
    int gw = (blockIdx.x * 256 + threadIdx.x) >> 6;   // one node per wave
    int lane = threadIdx.x & 63;
    if (gw >= N_NODES) return;
    unsigned beg = row_ptr[gw], end = row_ptr[gw + 1];
    float a0 = 0.f, a1 = 0.f;
    unsigned e = beg;
    for (; e + 4 <= end; e += 4) {
        unsigned s0 = edge_src[e + 0];
        unsigned s1 = edge_src[e + 1];
        unsigned s2 = edge_src[e + 2];
        unsigned s3 = edge_src[e + 3];
        float n0 = nsrc[s0], n1 = nsrc[s1], n2 = nsrc[s2], n3 = nsrc[s3];
        float2 v0 = *(const float2*)(feat + (size_t)s0 * IN_DIM + 2 * lane);
        float2 v1 = *(const float2*)(feat + (size_t)s1 * IN_DIM + 2 * lane);
        float2 v2 = *(const float2*)(feat + (size_t)s2 * IN_DIM + 2 * lane);
        float2 v3 = *(const float2*)(feat + (size_t)s3 * IN_DIM + 2 * lane);
        a0 = fmaf(v0.x, n0, a0); a1 = fmaf(v0.y, n0, a1);
        a0 = fmaf(v1.x, n1, a0); a1 = fmaf(v1.y, n1, a1);
        a0 = fmaf(v2.x, n2, a0); a1 = fmaf(v2.y, n2, a1);
        a0 = fmaf(v3.x, n3, a0); a1 = fmaf(v3.y, n3, a1);
    }
    for (; e < end; ++e) {
        unsigned s = edge_src[e];
        float ns = nsrc[s];
        float2 v = *(const float2*)(feat + (size_t)s * IN_DIM + 2 * lane);
        a0 = fmaf(v.x, ns, a0); a1 = fmaf(v.y, ns, a1);
    }
    float nd = rsqrtf(fmaxf((float)(end - beg), 1.0f));
    ushort2 o;
    o.x = (ushort)f2bf(a0 * nd);
    o.y = (ushort)f2bf(a1 * nd);
    *(ushort2*)(aggb + (size_t)gw * IN_DIM + 2 * lane) = o;
}

// ---------------------------------------------------------------------------
// Kernel 6: MFMA GEMM1 + LN + ReLU + MFMA GEMM2 + biases -> out
// Block 256 (4 waves), 64 rows/block, 16 rows/wave, full 256 cols per wave.
// 16x16x32 bf16 MFMA; A row = lane&15, k = (lane>>4)*8+j; C/D col = lane&15,
// row = (lane>>4)*4+reg (HW-verified mapping).
// ---------------------------------------------------------------------------
__global__ __launch_bounds__(256)
void gemm_kernel(const ushort* __restrict__ aggb, const float* __restrict__ feat,
                 const ushort* __restrict__ Wt, const ushort* __restrict__ sWt,
                 const float* __restrict__ bvec, const float* __restrict__ gamma,
                 const float* __restrict__ beta, const float* __restrict__ skipb,
                 float* __restrict__ out) {
    const int tid  = threadIdx.x;
    const int wid  = tid >> 6;
    const int lane = tid & 63;
    const int c = lane & 15;
    const int g = lane >> 4;
    const int row0 = blockIdx.x * 64 + wid * 16;
    const int arow = row0 + c;
    const bool arow_ok = arow < N_NODES;

    f32x4 acc[16];
    #pragma unroll
    for (int n = 0; n < 16; ++n) {
        float bb = bvec[n * 16 + c];     // bias is per-column
        acc[n] = (f32x4){bb, bb, bb, bb};
    }

    // ---- GEMM 1: agg_bf16 @ W ----------------------------------------------
    #pragma unroll
    for (int ks = 0; ks < 4; ++ks) {
        bf16x8 a = {};
        if (arow_ok)
            a = *(const bf16x8*)(aggb + (size_t)arow * IN_DIM + ks * 32 + g * 8);
        #pragma unroll
        for (int n = 0; n < 16; ++n) {
            bf16x8 b = *(const bf16x8*)(Wt + (size_t)(n * 16 + c) * IN_DIM + ks * 32 + g * 8);
            acc[n] = __builtin_amdgcn_mfma_f32_16x16x32_bf16(a, b, acc[n], 0, 0, 0);
        }
    }

    // ---- LayerNorm + ReLU ---------------------------------------------------
    {
        float s1[4] = {0.f, 0.f, 0.f, 0.f};
        float s2[4] = {0.f, 0.f, 0.f, 0.f};
        #pragma unroll
        for (int n = 0; n < 16; ++n) {
            #pragma unroll
            for (int j = 0; j < 4; ++j) {
                s1[j] += acc[n][j];
                s2[j] = fmaf(acc[n][j], acc[n][j], s2[j]);
            }
        }
        #pragma unroll
        for (int m = 1; m <= 8; m <<= 1) {
            #pragma unroll
            for (int j = 0; j < 4; ++j) {
                s1[j] += __shfl_xor(s1[j], m, 64);
                s2[j] += __shfl_xor(s2[j], m, 64);
            }
        }
        float mu[4], rstd[4];
        #pragma unroll
        for (int j = 0; j < 4; ++j) {
            mu[j] = s1[j] * (1.f / HID_DIM);
            float var = s2[j] * (1.f / HID_DIM) - mu[j] * mu[j];
            rstd[j] = rsqrtf(var + LN_EPS);
        }
        #pragma unroll
        for (int n = 0; n < 16; ++n) {
            float ga = gamma[n * 16 + c];
            float be = beta[n * 16 + c];
            #pragma unroll
            for (int j = 0; j < 4; ++j)
                acc[n][j] = fmaxf(fmaf((acc[n][j] - mu[j]) * rstd[j], ga, be), 0.f);
        }
    }

    // ---- GEMM 2: feat(bf16 cvt) @ skipW, accumulate on relu(ln) -------------
    #pragma unroll
    for (int ks = 0; ks < 4; ++ks) {
        bf16x8 a = {};
        if (arow_ok) {
            const float* fp = feat + (size_t)arow * IN_DIM + ks * 32 + g * 8;
            float4 u = *(const float4*)fp;
            float4 v = *(const float4*)(fp + 4);
            a[0] = f2bf(u.x); a[1] = f2bf(u.y); a[2] = f2bf(u.z); a[3] = f2bf(u.w);
            a[4] = f2bf(v.x); a[5] = f2bf(v.y); a[6] = f2bf(v.z); a[7] = f2bf(v.w);
        }
        #pragma unroll
        for (int n = 0; n < 16; ++n) {
            bf16x8 b = *(const bf16x8*)(sWt + (size_t)(n * 16 + c) * IN_DIM + ks * 32 + g * 8);
            acc[n] = __builtin_amdgcn_mfma_f32_16x16x32_bf16(a, b, acc[n], 0, 0, 0);
        }
    }

    // ---- + skip_b, store -----------------------------------------------------
    #pragma unroll
    for (int n = 0; n < 16; ++n) {
        float sb = skipb[n * 16 + c];
        #pragma unroll
        for (int j = 0; j < 4; ++j) {
            int row = row0 + g * 4 + j;
            if (row < N_NODES)
                out[(size_t)row * HID_DIM + n * 16 + c] = acc[n][j] + sb;
        }
    }
}

// ---------------------------------------------------------------------------
extern "C" void kernel_launch(void* const* d_in, const int* in_sizes, int n_in,
                              void* d_out, int out_size, void* d_ws, size_t ws_size,
                              hipStream_t stream) {
    const float* feat  = (const float*)d_in[0];
    const int*   src   = (const int*)d_in[1];
    const int*   dst   = (const int*)d_in[2];
    const float* W     = (const float*)d_in[3];
    const float* bvec  = (const float*)d_in[4];
    const float* gamma = (const float*)d_in[5];
    const float* beta  = (const float*)d_in[6];
    const float* skipW = (const float*)d_in[7];
    const float* skipb = (const float*)d_in[8];
    float* out = (float*)d_out;

    // workspace layout (≈34 MB, all segments 16B-aligned where vector-accessed)
    char* ws = (char*)d_ws;
    ushort*   aggb     = (ushort*)ws;                             // N*128 bf16 = 25.6 MB
    ushort*   Wt       = aggb + (size_t)N_NODES * IN_DIM;         // 32768 bf16
    ushort*   sWt      = Wt + IN_DIM * HID_DIM;                   // 32768 bf16
    unsigned* deg_out  = (unsigned*)(sWt + IN_DIM * HID_DIM);     // N
    unsigned* deg_in   = deg_out + N_NODES;                       // N
    unsigned* fill     = deg_in + N_NODES;                        // N
    unsigned* row_ptr  = fill + N_NODES;                          // N+4 (padded for align)
    float*    nsrc     = (float*)(row_ptr + N_NODES + 4);         // N
    unsigned* edge_src = (unsigned*)(nsrc + N_NODES);             // E

    hipMemsetAsync(deg_out, 0, (size_t)3 * N_NODES * 4, stream);

    deg_kernel<<<(N_EDGES + 255) / 256, 256, 0, stream>>>(src, dst, deg_out, deg_in);

    wcvt_kernel<<<(IN_DIM * HID_DIM + 255) / 256, 256, 0, stream>>>(W, skipW, Wt, sWt);

    scan_kernel<<<1, 1024, 0, stream>>>(deg_in, deg_out, row_ptr, nsrc);

    fill_kernel<<<(N_EDGES + 255) / 256, 256, 0, stream>>>(src, dst, row_ptr, fill, edge_src);

    spmm_kernel<<<(N_NODES * 64 + 255) / 256, 256, 0, stream>>>(feat, row_ptr, edge_src, nsrc, aggb);

    gemm_kernel<<<(N_NODES + 63) / 64, 256, 0, stream>>>(
        aggb, feat, Wt, sWt, bvec, gamma, beta, skipb, out);
}

// Round 4
// 502.942 us; speedup vs baseline: 6.0929x; 1.0876x over previous
//
#include <hip/hip_runtime.h>
#include <hip/hip_bf16.h>

#define N_NODES 100000
#define N_EDGES 1600000
#define IN_DIM 128
#define HID_DIM 256
#define LN_EPS 1e-5f
#define NT (N_NODES / 16)   // 6250 row-tiles, exact

typedef short bf16x8 __attribute__((ext_vector_type(8)));
typedef float f32x4  __attribute__((ext_vector_type(4)));

static __device__ __forceinline__ short f2bf(float x) {
    return __builtin_bit_cast(short, __float2bfloat16(x));  // RNE round
}

// ---------------------------------------------------------------------------
// Kernel 1: degree counts
// ---------------------------------------------------------------------------
__global__ void deg_kernel(const int* __restrict__ src, const int* __restrict__ dst,
                           unsigned* __restrict__ deg_out, unsigned* __restrict__ deg_in) {
    int e = blockIdx.x * blockDim.x + threadIdx.x;
    if (e < N_EDGES) {
        atomicAdd(&deg_out[src[e]], 1u);
        atomicAdd(&deg_in[dst[e]], 1u);
    }
}

// ---------------------------------------------------------------------------
// Kernel 2: single-block exclusive scan (4 elems/thread) -> row_ptr
// ---------------------------------------------------------------------------
__global__ __launch_bounds__(1024)
void scan_kernel(const unsigned* __restrict__ deg_in, unsigned* __restrict__ row_ptr) {
    __shared__ unsigned wsum[16];
    __shared__ unsigned carry_s;
    if (threadIdx.x == 0) carry_s = 0;
    __syncthreads();
    const int lane = threadIdx.x & 63;
    const int wid  = threadIdx.x >> 6;
    for (int base = 0; base < N_NODES; base += 4096) {
        int i0 = base + threadIdx.x * 4;
        unsigned d0 = 0, d1 = 0, d2 = 0, d3 = 0;
        if (i0 < N_NODES) {  // N_NODES % 4 == 0 -> quad fully in-range
            uint4 v = *(const uint4*)(deg_in + i0);
            d0 = v.x; d1 = v.y; d2 = v.z; d3 = v.w;
        }
        unsigned t = d0 + d1 + d2 + d3;
        unsigned x = t;
        #pragma unroll
        for (int d = 1; d < 64; d <<= 1) {
            unsigned tt = __shfl_up(x, d, 64);
            if (lane >= d) x += tt;
        }
        if (lane == 63) wsum[wid] = x;
        __syncthreads();
        if (threadIdx.x == 0) {
            unsigned run = carry_s;
            #pragma unroll
            for (int w = 0; w < 16; ++w) { unsigned tmp = wsum[w]; wsum[w] = run; run += tmp; }
            carry_s = run;
        }
        __syncthreads();
        if (i0 < N_NODES) {
            unsigned b = wsum[wid] + (x - t);
            uint4 rp;
            rp.x = b; rp.y = b + d0; rp.z = b + d0 + d1; rp.w = b + d0 + d1 + d2;
            *(uint4*)(row_ptr + i0) = rp;
        }
        __syncthreads();
    }
    if (threadIdx.x == 0) row_ptr[N_NODES] = carry_s;
}

// ---------------------------------------------------------------------------
// Kernel 3: CSR fill (bucket edges by dst)
// ---------------------------------------------------------------------------
__global__ void fill_kernel(const int* __restrict__ src, const int* __restrict__ dst,
                            const unsigned* __restrict__ row_ptr,
                            unsigned* __restrict__ fill, unsigned* __restrict__ edge_src) {
    int e = blockIdx.x * blockDim.x + threadIdx.x;
    if (e < N_EDGES) {
        int d = dst[e];
        unsigned pos = row_ptr[d] + atomicAdd(&fill[d], 1u);
        edge_src[pos] = (unsigned)src[e];
    }
}

// ---------------------------------------------------------------------------
// Kernel 4: W / skipW -> bf16, transposed to [HID_DIM][IN_DIM]
// ---------------------------------------------------------------------------
__global__ void wcvt_kernel(const float* __restrict__ W, const float* __restrict__ sW,
                            ushort* __restrict__ Wt, ushort* __restrict__ sWt) {
    int id = blockIdx.x * blockDim.x + threadIdx.x;
    if (id < IN_DIM * HID_DIM) {
        int k = id & (IN_DIM - 1);
        int n = id >> 7;
        Wt[n * IN_DIM + k]  = (ushort)f2bf(W[k * HID_DIM + n]);
        sWt[n * IN_DIM + k] = (ushort)f2bf(sW[k * HID_DIM + n]);
    }
}

// ---------------------------------------------------------------------------
// Kernel 5: featn = bf16(feat * norm_src)  (norm folded into gather table)
// one float4 per thread
// ---------------------------------------------------------------------------
__global__ void fcvt_kernel(const float* __restrict__ feat,
                            const unsigned* __restrict__ deg_out,
                            ushort* __restrict__ featn) {
    int id = blockIdx.x * blockDim.x + threadIdx.x;
    if (id < N_NODES * (IN_DIM / 4)) {
        int row = id >> 5;                       // 32 quads per row
        float ns = rsqrtf(fmaxf((float)deg_out[row], 1.f));
        float4 v = ((const float4*)feat)[id];
        ushort4 o;
        o.x = (ushort)f2bf(v.x * ns);
        o.y = (ushort)f2bf(v.y * ns);
        o.z = (ushort)f2bf(v.z * ns);
        o.w = (ushort)f2bf(v.w * ns);
        ((ushort4*)featn)[id] = o;
    }
}

// ---------------------------------------------------------------------------
// Kernel 6: row-per-wave gather SpMM over bf16 featn -> aggb (bf16)
// inner loop is pure adds (norm_src pre-folded); norm_dst applied at the end
// ---------------------------------------------------------------------------
__global__ __launch_bounds__(256)
void spmm_kernel(const ushort* __restrict__ featn,
                 const unsigned* __restrict__ row_ptr, const unsigned* __restrict__ edge_src,
                 unsigned* __restrict__ aggb_u32) {
    int gw = (blockIdx.x * 256 + threadIdx.x) >> 6;   // one node per wave
    int lane = threadIdx.x & 63;
    if (gw >= N_NODES) return;
    unsigned beg = row_ptr[gw], end = row_ptr[gw + 1];
    float a0 = 0.f, a1 = 0.f;
    unsigned e = beg;
    for (; e + 4 <= end; e += 4) {
        unsigned s0 = edge_src[e + 0];
        unsigned s1 = edge_src[e + 1];
        unsigned s2 = edge_src[e + 2];
        unsigned s3 = edge_src[e + 3];
        unsigned v0 = *(const unsigned*)(featn + (size_t)s0 * IN_DIM + 2 * lane);
        unsigned v1 = *(const unsigned*)(featn + (size_t)s1 * IN_DIM + 2 * lane);
        unsigned v2 = *(const unsigned*)(featn + (size_t)s2 * IN_DIM + 2 * lane);
        unsigned v3 = *(const unsigned*)(featn + (size_t)s3 * IN_DIM + 2 * lane);
        a0 += __builtin_bit_cast(float, v0 << 16);
        a1 += __builtin_bit_cast(float, v0 & 0xffff0000u);
        a0 += __builtin_bit_cast(float, v1 << 16);
        a1 += __builtin_bit_cast(float, v1 & 0xffff0000u);
        a0 += __builtin_bit_cast(float, v2 << 16);
        a1 += __builtin_bit_cast(float, v2 & 0xffff0000u);
        a0 += __builtin_bit_cast(float, v3 << 16);
        a1 += __builtin_bit_cast(float, v3 & 0xffff0000u);
    }
    for (; e < end; ++e) {
        unsigned s = edge_src[e];
        unsigned v = *(const unsigned*)(featn + (size_t)s * IN_DIM + 2 * lane);
        a0 += __builtin_bit_cast(float, v << 16);
        a1 += __builtin_bit_cast(float, v & 0xffff0000u);
    }
    float nd = rsqrtf(fmaxf((float)(end - beg), 1.0f));
    unsigned lo = (unsigned)(ushort)f2bf(a0 * nd);
    unsigned hi = (unsigned)(ushort)f2bf(a1 * nd);
    aggb_u32[(size_t)gw * (IN_DIM / 2) + lane] = lo | (hi << 16);
}

// ---------------------------------------------------------------------------
// Kernel 7: MFMA GEMM1 + LN + ReLU + MFMA GEMM2 + biases -> out
// 1024 threads = 16 waves. Wave w owns fixed col-strip [w*16, w*16+16);
// B fragments for BOTH GEMMs live in registers (loaded once).
// Block grid-strides over 16-row tiles; LN reduced across waves via LDS.
// ---------------------------------------------------------------------------
__global__ __launch_bounds__(1024)
void gemm_kernel(const ushort* __restrict__ aggb, const float* __restrict__ feat,
                 const ushort* __restrict__ Wt, const ushort* __restrict__ sWt,
                 const float* __restrict__ bvec, const float* __restrict__ gamma,
                 const float* __restrict__ beta, const float* __restrict__ skipb,
                 float* __restrict__ out) {
    __shared__ float2 red[16][17];   // [wave][row], padded to break bank aliasing
    __shared__ float2 mures[16];     // per-row (mu, rstd)
    const int tid  = threadIdx.x;
    const int w    = tid >> 6;       // wave 0..15
    const int lane = tid & 63;
    const int c    = lane & 15;
    const int g    = lane >> 4;
    const int col  = w * 16 + c;     // fixed output column

    const float bb = bvec[col], ga = gamma[col], be = beta[col], sb = skipb[col];

    bf16x8 bW[4], bS[4];
    #pragma unroll
    for (int ks = 0; ks < 4; ++ks) {
        bW[ks] = *(const bf16x8*)(Wt  + (size_t)col * IN_DIM + ks * 32 + g * 8);
        bS[ks] = *(const bf16x8*)(sWt + (size_t)col * IN_DIM + ks * 32 + g * 8);
    }

    for (int tile = blockIdx.x; tile < NT; tile += gridDim.x) {
        const int row0 = tile * 16;

        // ---- GEMM 1: aggb @ W + b ------------------------------------------
        f32x4 acc = (f32x4){bb, bb, bb, bb};
        #pragma unroll
        for (int ks = 0; ks < 4; ++ks) {
            bf16x8 a = *(const bf16x8*)(aggb + (size_t)(row0 + c) * IN_DIM + ks * 32 + g * 8);
            acc = __builtin_amdgcn_mfma_f32_16x16x32_bf16(a, bW[ks], acc, 0, 0, 0);
        }

        // ---- LN stats: in-wave reduce over 16 cols, then cross-wave --------
        float s1[4], s2[4];
        #pragma unroll
        for (int j = 0; j < 4; ++j) { s1[j] = acc[j]; s2[j] = acc[j] * acc[j]; }
        #pragma unroll
        for (int m = 1; m <= 8; m <<= 1) {
            #pragma unroll
            for (int j = 0; j < 4; ++j) {
                s1[j] += __shfl_xor(s1[j], m, 64);
                s2[j] += __shfl_xor(s2[j], m, 64);
            }
        }
        if (c == 0) {
            #pragma unroll
            for (int j = 0; j < 4; ++j)
                red[w][g * 4 + j] = make_float2(s1[j], s2[j]);
        }
        __syncthreads();
        if (tid < 256) {
            int r  = tid >> 4;    // row 0..15
            int ww = tid & 15;    // wave partial index
            float2 v = red[ww][r];
            float t1 = v.x, t2 = v.y;
            #pragma unroll
            for (int m = 1; m <= 8; m <<= 1) {
                t1 += __shfl_xor(t1, m, 64);
                t2 += __shfl_xor(t2, m, 64);
            }
            if (ww == 0) {
                float mu  = t1 * (1.f / HID_DIM);
                float var = t2 * (1.f / HID_DIM) - mu * mu;
                mures[r] = make_float2(mu, rsqrtf(var + LN_EPS));
            }
        }
        __syncthreads();

        // ---- LN + ReLU ------------------------------------------------------
        #pragma unroll
        for (int j = 0; j < 4; ++j) {
            float2 mr = mures[g * 4 + j];
            acc[j] = fmaxf(fmaf((acc[j] - mr.x) * mr.y, ga, be), 0.f);
        }

        // ---- GEMM 2: feat(bf16 cvt) @ skipW, accumulate ---------------------
        #pragma unroll
        for (int ks = 0; ks < 4; ++ks) {
            const float* fp = feat + (size_t)(row0 + c) * IN_DIM + ks * 32 + g * 8;
            float4 u = *(const float4*)fp;
            float4 v = *(const float4*)(fp + 4);
            bf16x8 a;
            a[0] = f2bf(u.x); a[1] = f2bf(u.y); a[2] = f2bf(u.z); a[3] = f2bf(u.w);
            a[4] = f2bf(v.x); a[5] = f2bf(v.y); a[6] = f2bf(v.z); a[7] = f2bf(v.w);
            acc = __builtin_amdgcn_mfma_f32_16x16x32_bf16(a, bS[ks], acc, 0, 0, 0);
        }

        // ---- + skip_b, store -------------------------------------------------
        #pragma unroll
        for (int j = 0; j < 4; ++j)
            out[(size_t)(row0 + g * 4 + j) * HID_DIM + col] = acc[j] + sb;
    }
}

// ---------------------------------------------------------------------------
extern "C" void kernel_launch(void* const* d_in, const int* in_sizes, int n_in,
                              void* d_out, int out_size, void* d_ws, size_t ws_size,
                              hipStream_t stream) {
    const float* feat  = (const float*)d_in[0];
    const int*   src   = (const int*)d_in[1];
    const int*   dst   = (const int*)d_in[2];
    const float* W     = (const float*)d_in[3];
    const float* bvec  = (const float*)d_in[4];
    const float* gamma = (const float*)d_in[5];
    const float* beta  = (const float*)d_in[6];
    const float* skipW = (const float*)d_in[7];
    const float* skipb = (const float*)d_in[8];
    float* out = (float*)d_out;

    // workspace layout (≈59.4 MB)
    char* ws = (char*)d_ws;
    ushort*   aggb     = (ushort*)ws;                             // N*128 bf16 = 25.6 MB
    ushort*   featn    = aggb + (size_t)N_NODES * IN_DIM;         // N*128 bf16 = 25.6 MB
    ushort*   Wt       = featn + (size_t)N_NODES * IN_DIM;        // 32768 bf16
    ushort*   sWt      = Wt + IN_DIM * HID_DIM;                   // 32768 bf16
    unsigned* deg_out  = (unsigned*)(sWt + IN_DIM * HID_DIM);     // N
    unsigned* deg_in   = deg_out + N_NODES;                       // N
    unsigned* fill     = deg_in + N_NODES;                        // N
    unsigned* row_ptr  = fill + N_NODES;                          // N+4
    unsigned* edge_src = row_ptr + N_NODES + 4;                   // E

    hipMemsetAsync(deg_out, 0, (size_t)3 * N_NODES * 4, stream);

    deg_kernel<<<(N_EDGES + 255) / 256, 256, 0, stream>>>(src, dst, deg_out, deg_in);

    wcvt_kernel<<<(IN_DIM * HID_DIM + 255) / 256, 256, 0, stream>>>(W, skipW, Wt, sWt);

    scan_kernel<<<1, 1024, 0, stream>>>(deg_in, row_ptr);

    fill_kernel<<<(N_EDGES + 255) / 256, 256, 0, stream>>>(src, dst, row_ptr, fill, edge_src);

    fcvt_kernel<<<(N_NODES * (IN_DIM / 4) + 255) / 256, 256, 0, stream>>>(feat, deg_out, featn);

    spmm_kernel<<<(N_NODES * 64 + 255) / 256, 256, 0, stream>>>(featn, row_ptr, edge_src,
                                                                (unsigned*)aggb);

    gemm_kernel<<<512, 1024, 0, stream>>>(aggb, feat, Wt, sWt, bvec, gamma, beta, skipb, out);
}